// Round 2
// 2339.167 us; speedup vs baseline: 1.0944x; 1.0944x over previous
//
#include <hip/hip_runtime.h>
#include <hip/hip_bf16.h>

// ---------------- constants ----------------
#define BATCH 4
#define TIN0 160000
#define DMODEL 768
#define NLAYER 12
#define FFDIM 2048
#define NCLS 100
#define SMAX_ 64
#define TP_ 499

typedef __attribute__((ext_vector_type(8))) short short8;
typedef __attribute__((ext_vector_type(4))) float f32x4;

__device__ inline ushort f2b(float f) { __hip_bfloat16 h = __float2bfloat16(f); return *(ushort*)&h; }
__device__ inline float b2f(ushort u) { __hip_bfloat16 h = *(__hip_bfloat16*)&u; return __bfloat162float(h); }

__device__ inline void gl_lds16(const ushort* g, ushort* l) {
    __builtin_amdgcn_global_load_lds((const __attribute__((address_space(1))) unsigned int*)g,
                                     (__attribute__((address_space(3))) unsigned int*)l, 16, 0, 0);
}

// ---------------- reduction helpers ----------------
__device__ inline float wave_reduce_sum(float v) {
#pragma unroll
    for (int off = 32; off > 0; off >>= 1) v += __shfl_down(v, off, 64);
    return v;
}
__device__ inline float wave_reduce_max(float v) {
#pragma unroll
    for (int off = 32; off > 0; off >>= 1) v = fmaxf(v, __shfl_down(v, off, 64));
    return v;
}
__device__ inline float block_reduce_sum(float v, float* scratch) {
    v = wave_reduce_sum(v);
    int wid = threadIdx.x >> 6;
    if ((threadIdx.x & 63) == 0) scratch[wid] = v;
    __syncthreads();
    float r = scratch[0] + scratch[1] + scratch[2] + scratch[3];
    __syncthreads();
    return r;
}
__device__ inline float block_reduce_max(float v, float* scratch) {
    v = wave_reduce_max(v);
    int wid = threadIdx.x >> 6;
    if ((threadIdx.x & 63) == 0) scratch[wid] = v;
    __syncthreads();
    float r = fmaxf(fmaxf(scratch[0], scratch[1]), fmaxf(scratch[2], scratch[3]));
    __syncthreads();
    return r;
}

// =================================================================
// Conv MFMA, kw-inner (unchanged math; batch-merged via blockIdx.z)
// =================================================================
template <int KW>
__global__ __launch_bounds__(256) void convT_mfma(
    const ushort* __restrict__ A,
    const ushort* __restrict__ Wc,
    const float* __restrict__ bias,
    ushort* __restrict__ outp,
    int Cin, int Cout, int Tout,
    int tBase, int uBase, int uMax,
    long aStride, long oStride) {
    constexpr int EB = 132;            // even-row region (rows)
    __shared__ ushort sA[288 * 64];    // 36.9 KB
    __shared__ ushort sB[KW * 128 * 32];
    const int tid = threadIdx.x;
    const int lane = tid & 63;
    const int wv = tid >> 6;
    const int mrow = lane & 15;
    const int kq = lane >> 4;
    const int t0 = tBase + blockIdx.x * 128;
    const int oc0 = blockIdx.y * 128;
    const ushort* Ab = A + (size_t)blockIdx.z * aStride;
    ushort* outb = outp + (size_t)blockIdx.z * oStride;
    const int K = KW * Cin;

    f32x4 acc[2][8];
#pragma unroll
    for (int s = 0; s < 2; s++)
#pragma unroll
        for (int n = 0; n < 8; n++) acc[s][n] = (f32x4){0.f, 0.f, 0.f, 0.f};

    const int nC8 = Cin >> 6;
    for (int c8 = 0; c8 < nC8; c8++) {
        const int ic0 = c8 << 6;
        // ---- stage A (even rows 0..131, odd rows 132..259; 288 padded) ----
#pragma unroll
        for (int rd = 0; rd < 9; rd++) {
            int slotBase = rd * 256 + wv * 64;
            int slot = slotBase + lane;
            int r = slot >> 3;
            int g = (slot & 7) ^ (r & 7);
            int u = (r < EB) ? (2 * t0 + 2 * r) : (2 * t0 + 2 * (r - EB) + 1);
            u -= uBase;
            if (u < 0) u = 0;
            if (u > uMax) u = uMax;
            gl_lds16(Ab + (size_t)u * Cin + ic0 + g * 8, &sA[slotBase * 8]);
        }
#pragma unroll
        for (int h = 0; h < 2; h++) {
            // ---- stage B for this 32-k half ----
#pragma unroll
            for (int rd = 0; rd < KW * 2; rd++) {
                int slotBase = rd * 256 + wv * 64;
                int slot = slotBase + lane;
                int r = slot >> 2;
                int g = (slot & 3) ^ ((r >> 1) & 3);
                int ocr = oc0 + (r & 127);
                if (ocr > Cout - 1) ocr = Cout - 1;
                int kwi = r >> 7;
                gl_lds16(Wc + (size_t)ocr * K + kwi * Cin + ic0 + h * 32 + g * 8,
                         &sB[slotBase * 8]);
            }
            __syncthreads();
#pragma unroll
            for (int kw = 0; kw < KW; kw++) {
                const int abase = (kw & 1) ? EB : 0;
                const int aoff = kw >> 1;
#pragma unroll
                for (int s = 0; s < 2; s++) {
                    int ar = abase + wv * 32 + s * 16 + mrow + aoff;
                    short8 af = *(const short8*)&sA[ar * 64 + (((h * 4 + kq) ^ (ar & 7)) * 8)];
#pragma unroll
                    for (int n = 0; n < 8; n++) {
                        int br = kw * 128 + n * 16 + mrow;
                        short8 bf = *(const short8*)&sB[br * 32 + ((kq ^ ((br >> 1) & 3)) * 8)];
                        acc[s][n] = __builtin_amdgcn_mfma_f32_16x16x32_bf16(af, bf, acc[s][n], 0, 0, 0);
                    }
                }
            }
            __syncthreads();
        }
    }

    // ---- epilogue (verified C-layout: row=kq*4+r -> t, col=mrow -> oc) ----
    float bz[8];
#pragma unroll
    for (int n = 0; n < 8; n++) {
        int oc = oc0 + n * 16 + mrow;
        bz[n] = (oc < Cout) ? bias[oc] : 0.f;
    }
#pragma unroll
    for (int s = 0; s < 2; s++) {
        int tb = t0 + wv * 32 + s * 16 + kq * 4;
#pragma unroll
        for (int n = 0; n < 8; n++) {
            int oc = oc0 + n * 16 + mrow;
            if (oc >= Cout) continue;
#pragma unroll
            for (int r = 0; r < 4; r++) {
                int t = tb + r;
                if (t < Tout) outb[(size_t)t * Cout + oc] = f2b(fmaxf(acc[s][n][r] + bz[n], 0.f));
            }
        }
    }
}

// =================================================================
// Generic MFMA GEMM (head projection only), BF32 weight path.
// =================================================================
template <int KW, int STRIDE, int RELU, int OBF, int BF32>
__global__ __launch_bounds__(256) void conv_mfma(
    const ushort* __restrict__ A,
    const ushort* __restrict__ Wc,
    const float* __restrict__ Wf,
    const float* __restrict__ bias,
    void* __restrict__ outv,
    int Cin, int Cout, int Tout, int tBase, int uBase,
    long aStride, long oStride) {
    const int K = KW * Cin;
    const int nCh = K >> 5;
    const int t0 = tBase + blockIdx.x * 128;
    const int oc0 = blockIdx.y * 128;
    const int b = blockIdx.z;
    const ushort* Ab = A + (size_t)b * aStride;
    __shared__ ushort sA[4096];
    __shared__ ushort sB[4096];
    const int tid = threadIdx.x;
    const int lane = tid & 63;
    const int wv = tid >> 6;
    const int rsub = lane >> 2;
    const int kgW = (lane & 3) ^ ((lane >> 3) & 3);
    const int mrow = lane & 15;
    const int kq = lane >> 4;
    const int slot8 = (mrow * 4 + (kq ^ ((mrow >> 1) & 3))) * 8;

    f32x4 acc[2][8];
#pragma unroll
    for (int s = 0; s < 2; s++)
#pragma unroll
        for (int n = 0; n < 8; n++) acc[s][n] = (f32x4){0.f, 0.f, 0.f, 0.f};

    for (int c = 0; c < nCh; c++) {
#pragma unroll
        for (int j = 0; j < 2; j++) {
            int t = t0 + j * 64 + wv * 16 + rsub;
            if (t > Tout - 1) t = Tout - 1;
            int u = STRIDE * t - uBase;
            gl_lds16(Ab + (size_t)u * Cin + c * 32 + kgW * 8, &sA[(j * 64 + wv * 16) * 32]);
        }
#pragma unroll
        for (int j = 0; j < 2; j++) {
            int rowb = oc0 + j * 64 + wv * 16 + rsub;
            if (rowb > Cout - 1) rowb = Cout - 1;
            if (BF32) {
                const float* wp = Wf + (size_t)rowb * K + c * 32 + kgW * 8;
                float4 w0_ = *(const float4*)wp;
                float4 w1_ = *(const float4*)(wp + 4);
                short8 vals;
                vals[0] = (short)f2b(w0_.x); vals[1] = (short)f2b(w0_.y);
                vals[2] = (short)f2b(w0_.z); vals[3] = (short)f2b(w0_.w);
                vals[4] = (short)f2b(w1_.x); vals[5] = (short)f2b(w1_.y);
                vals[6] = (short)f2b(w1_.z); vals[7] = (short)f2b(w1_.w);
                *(short8*)&sB[(j * 64 + wv * 16) * 32 + lane * 8] = vals;
            } else {
                gl_lds16(Wc + (size_t)rowb * K + c * 32 + kgW * 8, &sB[(j * 64 + wv * 16) * 32]);
            }
        }
        __syncthreads();
        short8 a0 = *(const short8*)&sA[(wv * 32 + 0) * 32 + slot8];
        short8 a1 = *(const short8*)&sA[(wv * 32 + 16) * 32 + slot8];
#pragma unroll
        for (int n = 0; n < 8; n++) {
            short8 bf = *(const short8*)&sB[(n * 16) * 32 + slot8];
            acc[0][n] = __builtin_amdgcn_mfma_f32_16x16x32_bf16(a0, bf, acc[0][n], 0, 0, 0);
            acc[1][n] = __builtin_amdgcn_mfma_f32_16x16x32_bf16(a1, bf, acc[1][n], 0, 0, 0);
        }
        __syncthreads();
    }
    float* outf = (float*)outv + (size_t)b * oStride;
    ushort* outh = (ushort*)outv + (size_t)b * oStride;
    float bz[8];
#pragma unroll
    for (int n = 0; n < 8; n++) {
        int oc = oc0 + n * 16 + mrow;
        bz[n] = (oc < Cout) ? bias[oc] : 0.f;
    }
#pragma unroll
    for (int s = 0; s < 2; s++) {
        int tb = t0 + wv * 32 + s * 16 + kq * 4;
#pragma unroll
        for (int n = 0; n < 8; n++) {
            int oc = oc0 + n * 16 + mrow;
            if (oc >= Cout) continue;
#pragma unroll
            for (int r = 0; r < 4; r++) {
                int t = tb + r;
                if (t < Tout) {
                    float v = acc[s][n][r] + bz[n];
                    if (RELU) v = fmaxf(v, 0.f);
                    if (OBF) outh[(size_t)t * Cout + oc] = f2b(v);
                    else outf[(size_t)t * Cout + oc] = v;
                }
            }
        }
    }
}

// =================================================================
// Split-K GEMM v2 (transformer): 256-row single t-tile, double-buffered
// 2-phase prefetch (issue next-chunk loads before current MFMA block).
// A bf16 [256][K], W fp32 [M][K] -> fp32 partial slabs
// outp[kc*oSlab + t*M + oc]; kc==0 slab carries bias.
// =================================================================
__global__ __launch_bounds__(256) void gemm_sk2(
    const ushort* __restrict__ A, const float* __restrict__ Wf,
    const float* __restrict__ bias, float* __restrict__ outp,
    int M, int K, int KCH, long oSlab) {
    __shared__ ushort sA[2][8192];   // 256 rows x 32 k (bf16), per buffer 16 KB
    __shared__ ushort sB[2][4096];   // 128 rows x 32 k, per buffer 8 KB
    const int tid = threadIdx.x;
    const int lane = tid & 63;
    const int wv = tid >> 6;
    const int rsub = lane >> 2;
    const int kgW = (lane & 3) ^ ((lane >> 3) & 3);
    const int mrow = lane & 15;
    const int kq = lane >> 4;
    const int slot8 = (mrow * 4 + (kq ^ ((mrow >> 1) & 3))) * 8;
    const int oc0 = blockIdx.y * 128;
    const int kc = blockIdx.z;
    const int k0 = kc * KCH;
    const int nIt = KCH >> 5;

    f32x4 acc[4][8];
#pragma unroll
    for (int s = 0; s < 4; s++)
#pragma unroll
        for (int n = 0; n < 8; n++) acc[s][n] = (f32x4){0.f, 0.f, 0.f, 0.f};

    float4 wr[2][2];

    auto stageA = [&](int buf, int kk) {
#pragma unroll
        for (int j = 0; j < 4; j++) {
            int t = j * 64 + wv * 16 + rsub;
            gl_lds16(A + (size_t)t * K + kk + kgW * 8, &sA[buf][(j * 64 + wv * 16) * 32]);
        }
    };
    auto wload = [&](int kk) {
#pragma unroll
        for (int j = 0; j < 2; j++) {
            int rowb = oc0 + j * 64 + wv * 16 + rsub;
            const float* wp = Wf + (size_t)rowb * K + kk + kgW * 8;
            wr[j][0] = *(const float4*)wp;
            wr[j][1] = *(const float4*)(wp + 4);
        }
    };
    auto wstore = [&](int buf) {
#pragma unroll
        for (int j = 0; j < 2; j++) {
            short8 vals;
            vals[0] = (short)f2b(wr[j][0].x); vals[1] = (short)f2b(wr[j][0].y);
            vals[2] = (short)f2b(wr[j][0].z); vals[3] = (short)f2b(wr[j][0].w);
            vals[4] = (short)f2b(wr[j][1].x); vals[5] = (short)f2b(wr[j][1].y);
            vals[6] = (short)f2b(wr[j][1].z); vals[7] = (short)f2b(wr[j][1].w);
            *(short8*)&sB[buf][(j * 64 + wv * 16) * 32 + lane * 8] = vals;
        }
    };

    // prologue: stage chunk 0 into buffer 0
    stageA(0, k0);
    wload(k0);
    wstore(0);
    __syncthreads();   // compiler drains vmcnt+lgkm here -> buf0 ready

    for (int c = 0; c < nIt; c++) {
        const int cur = c & 1;
        const int nxt = cur ^ 1;
        if (c + 1 < nIt) {
            stageA(nxt, k0 + ((c + 1) << 5));   // async A -> other LDS buffer
            wload(k0 + ((c + 1) << 5));         // W fp32 -> regs (in flight)
        }
        short8 a0 = *(const short8*)&sA[cur][(wv * 64 + 0) * 32 + slot8];
        short8 a1 = *(const short8*)&sA[cur][(wv * 64 + 16) * 32 + slot8];
        short8 a2 = *(const short8*)&sA[cur][(wv * 64 + 32) * 32 + slot8];
        short8 a3 = *(const short8*)&sA[cur][(wv * 64 + 48) * 32 + slot8];
#pragma unroll
        for (int n = 0; n < 8; n++) {
            short8 bf = *(const short8*)&sB[cur][(n * 16) * 32 + slot8];
            acc[0][n] = __builtin_amdgcn_mfma_f32_16x16x32_bf16(a0, bf, acc[0][n], 0, 0, 0);
            acc[1][n] = __builtin_amdgcn_mfma_f32_16x16x32_bf16(a1, bf, acc[1][n], 0, 0, 0);
            acc[2][n] = __builtin_amdgcn_mfma_f32_16x16x32_bf16(a2, bf, acc[2][n], 0, 0, 0);
            acc[3][n] = __builtin_amdgcn_mfma_f32_16x16x32_bf16(a3, bf, acc[3][n], 0, 0, 0);
        }
        if (c + 1 < nIt) wstore(nxt);   // regs arrived during MFMA; ds_write other buffer
        __syncthreads();                // drain: A(next) + B(next) landed
    }

    float* op = outp + (size_t)kc * oSlab;
#pragma unroll
    for (int s = 0; s < 4; s++) {
        int tb = wv * 64 + s * 16 + kq * 4;
#pragma unroll
        for (int n = 0; n < 8; n++) {
            int oc = oc0 + n * 16 + mrow;
            float bz = (kc == 0) ? bias[oc] : 0.f;
#pragma unroll
            for (int r = 0; r < 4; r++) {
                op[(size_t)(tb + r) * M + oc] = acc[s][n][r] + bz;
            }
        }
    }
}

// ---------------- relu(sum of nP slabs) -> bf16 ----------------
__global__ __launch_bounds__(256) void relu_cast(const float* __restrict__ p,
                                                 ushort* __restrict__ o,
                                                 long n, long slab, int nP) {
    for (long i = (long)blockIdx.x * 1024 + threadIdx.x; i < n; i += (long)gridDim.x * 1024) {
#pragma unroll
        for (int j = 0; j < 4; j++) {
            long k = i + (long)j * 256;
            if (k < n) {
                float v = 0.f;
                for (int q = 0; q < nP; q++) v += p[k + q * slab];
                o[k] = f2b(fmaxf(v, 0.f));
            }
        }
    }
}

// =================================================================
// conv0 as MFMA GEMM (batch-merged via blockIdx.z)
// =================================================================
__global__ __launch_bounds__(256) void conv0_mfma(const float* __restrict__ x,
                                                  const ushort* __restrict__ w0pad,
                                                  const float* __restrict__ b0,
                                                  ushort* __restrict__ c0,
                                                  int uBase, int nU, long oStride) {
    __shared__ ushort sA[4096];
    __shared__ ushort sB[4096];
    const int tid = threadIdx.x;
    const int lane = tid & 63;
    const int wv = tid >> 6;
    const int rsub = lane >> 2;
    const int kgW = (lane & 3) ^ ((lane >> 3) & 3);
    const int mrow = lane & 15;
    const int kq = lane >> 4;
    const int slot8 = (mrow * 4 + (kq ^ ((mrow >> 1) & 3))) * 8;
    const int r0 = blockIdx.x * 128;
    const int oc0 = blockIdx.y * 128;
    const float* xb = x + (size_t)blockIdx.z * TIN0;
    ushort* ob = c0 + (size_t)blockIdx.z * oStride;

    f32x4 acc[2][8];
#pragma unroll
    for (int s = 0; s < 2; s++)
#pragma unroll
        for (int n = 0; n < 8; n++) acc[s][n] = (f32x4){0.f, 0.f, 0.f, 0.f};

#pragma unroll
    for (int j = 0; j < 2; j++) {
        int r = r0 + j * 64 + wv * 16 + rsub;
        if (r > nU - 1) r = nU - 1;
        const float* xp = xb + (size_t)5 * (uBase + r);
        short8 vals = (short8){0, 0, 0, 0, 0, 0, 0, 0};
        if (kgW == 0) {
#pragma unroll
            for (int q = 0; q < 8; q++) vals[q] = (short)f2b(xp[q]);
        } else if (kgW == 1) {
            vals[0] = (short)f2b(xp[8]);
            vals[1] = (short)f2b(xp[9]);
        }
        *(short8*)&sA[(j * 64 + wv * 16) * 32 + lane * 8] = vals;
    }
#pragma unroll
    for (int j = 0; j < 2; j++) {
        int rowb = oc0 + j * 64 + wv * 16 + rsub;
        gl_lds16(w0pad + (size_t)rowb * 32 + kgW * 8, &sB[(j * 64 + wv * 16) * 32]);
    }
    __syncthreads();
    short8 a0 = *(const short8*)&sA[(wv * 32 + 0) * 32 + slot8];
    short8 a1 = *(const short8*)&sA[(wv * 32 + 16) * 32 + slot8];
#pragma unroll
    for (int n = 0; n < 8; n++) {
        short8 bf = *(const short8*)&sB[(n * 16) * 32 + slot8];
        acc[0][n] = __builtin_amdgcn_mfma_f32_16x16x32_bf16(a0, bf, acc[0][n], 0, 0, 0);
        acc[1][n] = __builtin_amdgcn_mfma_f32_16x16x32_bf16(a1, bf, acc[1][n], 0, 0, 0);
    }
#pragma unroll
    for (int s = 0; s < 2; s++) {
        int rb = r0 + wv * 32 + s * 16 + kq * 4;
#pragma unroll
        for (int n = 0; n < 8; n++) {
            int oc = oc0 + n * 16 + mrow;
            float bz = b0[oc];
#pragma unroll
            for (int r = 0; r < 4; r++) {
                int rr = rb + r;
                if (rr < nU) ob[(size_t)rr * 512 + oc] = f2b(fmaxf(acc[s][n][r] + bz, 0.f));
            }
        }
    }
}

// ---------------- conv-weight permute+cast ----------------
__global__ __launch_bounds__(256) void convw_kernel(
    const float* __restrict__ w1, const float* __restrict__ w2, const float* __restrict__ w3,
    const float* __restrict__ w4, const float* __restrict__ w5, const float* __restrict__ w6,
    const float* __restrict__ w0, ushort* __restrict__ dst, ushort* __restrict__ dw0) {
    const int z = blockIdx.y;
    const int COUTS[6] = {512, 512, 512, 512, 512, 768};
    const int KWS[6] = {3, 3, 3, 2, 2, 2};
    const long OFFS[6] = {0, 786432, 1572864, 2359296, 2883584, 3407872};
    const float* srcs[6] = {w1, w2, w3, w4, w5, w6};
    if (z == 6) {
        for (int o = blockIdx.x * 256 + threadIdx.x; o < 512 * 32; o += gridDim.x * 256) {
            int oc = o >> 5, q = o & 31;
            dw0[o] = (q < 10) ? f2b(w0[oc * 10 + q]) : (ushort)0;
        }
        return;
    }
    const float* src = srcs[z];
    ushort* d = dst + OFFS[z];
    const int Cin = 512, Kw = KWS[z];
    const int K = Cin * Kw;
    const long n = (long)COUTS[z] * K;
    for (long o = blockIdx.x * 256 + threadIdx.x; o < n; o += (long)gridDim.x * 256) {
        long oc = o / K;
        int rem = (int)(o - oc * K);
        int kw = rem / Cin, ic = rem - kw * Cin;
        d[o] = f2b(src[(oc * Cin + ic) * Kw + kw]);
    }
}

// ---------------- scores ----------------
__global__ __launch_bounds__(256) void scores_kernel(const ushort* __restrict__ feats,
                                                     const float* __restrict__ v,
                                                     float* __restrict__ scores) {
    int b = blockIdx.y;
    int t = blockIdx.x * 4 + (threadIdx.x >> 6);
    if (t >= TP_) return;
    int lane = threadIdx.x & 63;
    const ushort* f = feats + ((size_t)b * TP_ + t) * DMODEL + lane * 12;
    float acc = 0.f;
#pragma unroll
    for (int q = 0; q < 12; q++) acc = fmaf(b2f(f[q]), v[lane * 12 + q], acc);
    acc = wave_reduce_sum(acc);
    if (lane == 0) scores[b * TP_ + t] = acc;
}

// ---------------- per-segment softmax pooling + pos_emb ----------------
__global__ __launch_bounds__(256) void pool_kernel(const ushort* __restrict__ featsAll,
                                                   const float* __restrict__ scoresAll,
                                                   const int* __restrict__ seg_bounds,
                                                   const int* __restrict__ n_segs,
                                                   const float* __restrict__ pos_emb,
                                                   float* __restrict__ tokens,
                                                   ushort* __restrict__ tokens_bf) {
    __shared__ float scratch[4];
    __shared__ float wgt[512];
    int s = blockIdx.x, b = blockIdx.y, tid = threadIdx.x;
    float* tout = tokens + ((size_t)b * SMAX_ + s) * DMODEL;
    ushort* tbf = tokens_bf + ((size_t)b * SMAX_ + s) * DMODEL;
    int ns = n_segs[b];
    if (s >= ns) {
        for (int c = tid; c < DMODEL; c += 256) {
            float v = pos_emb[s * DMODEL + c];
            tout[c] = v; tbf[c] = f2b(v);
        }
        return;
    }
    const float* sc = scoresAll + b * TP_;
    int b0 = seg_bounds[b * (SMAX_ + 1) + s];
    int b1 = seg_bounds[b * (SMAX_ + 1) + s + 1];
    int st = min(max(b0, 0), TP_ - 1);
    int en = max(st + 1, min(max(b1, 0), TP_));
    float lm = -1e30f;
    for (int t = st + tid; t < en; t += 256) lm = fmaxf(lm, sc[t]);
    float m = block_reduce_max(lm, scratch);
    float ls = 0.f;
    for (int t = st + tid; t < en; t += 256) ls += __expf(sc[t] - m);
    float den = block_reduce_sum(ls, scratch);
    float inv = 1.f / den;
    for (int t = st + tid; t < en; t += 256) wgt[t - st] = __expf(sc[t] - m) * inv;
    __syncthreads();
    int len = en - st;
    const ushort* f = featsAll + ((size_t)b * TP_ + st) * DMODEL;
    float a0 = 0.f, a1 = 0.f, a2 = 0.f;
    for (int t = 0; t < len; t++) {
        float wv = wgt[t];
        const ushort* fr = f + (size_t)t * DMODEL;
        a0 = fmaf(wv, b2f(fr[tid]), a0);
        a1 = fmaf(wv, b2f(fr[tid + 256]), a1);
        a2 = fmaf(wv, b2f(fr[tid + 512]), a2);
    }
    float v0 = a0 + pos_emb[s * DMODEL + tid];
    float v1 = a1 + pos_emb[s * DMODEL + tid + 256];
    float v2 = a2 + pos_emb[s * DMODEL + tid + 512];
    tout[tid] = v0; tout[tid + 256] = v1; tout[tid + 512] = v2;
    tbf[tid] = f2b(v0); tbf[tid + 256] = f2b(v1); tbf[tid + 512] = f2b(v2);
}

// ---------------- attention: qkv from nP fp32 partial slabs ----------------
__global__ __launch_bounds__(256) void attn_kernel(const float* __restrict__ qkv_p,
                                                   const int* __restrict__ n_segs,
                                                   ushort* __restrict__ o, long slab, int nP) {
    __shared__ float sK[64][68];
    __shared__ float sV[64][68];
    __shared__ float sS[64][68];
    int h = blockIdx.x, b = blockIdx.y, tid = threadIdx.x;
    int ns = n_segs[b];
    const float* base = qkv_p + (size_t)b * 64 * 2304 + h * 64;
    for (int idx = tid; idx < 4096; idx += 256) {
        int s_ = idx >> 6, d = idx & 63;
        size_t kofs = (size_t)s_ * 2304 + 768 + d;
        size_t vofs = (size_t)s_ * 2304 + 1536 + d;
        float kv = 0.f, vv = 0.f;
        for (int p = 0; p < nP; p++) { kv += base[kofs + p * slab]; vv += base[vofs + p * slab]; }
        sK[s_][d] = kv; sV[s_][d] = vv;
    }
    __syncthreads();
    int qr = tid >> 2;
    int c0 = (tid & 3) * 16;
    const float* qrow = base + (size_t)qr * 2304;
    float acc[16];
#pragma unroll
    for (int j = 0; j < 16; j++) acc[j] = 0.f;
    for (int d = 0; d < 64; d += 4) {
        float4 qv = make_float4(0.f, 0.f, 0.f, 0.f);
        for (int p = 0; p < nP; p++) {
            float4 qp = *(const float4*)(qrow + p * slab + d);
            qv.x += qp.x; qv.y += qp.y; qv.z += qp.z; qv.w += qp.w;
        }
#pragma unroll
        for (int j = 0; j < 16; j++) {
            float4 kv = *(const float4*)&sK[c0 + j][d];
            acc[j] += qv.x * kv.x + qv.y * kv.y + qv.z * kv.z + qv.w * kv.w;
        }
    }
#pragma unroll
    for (int j = 0; j < 16; j++) {
        int kc = c0 + j;
        float vv = acc[j] * 0.125f;
        if (kc >= ns) vv = -1e9f;
        sS[qr][kc] = vv;
    }
    __syncthreads();
    if (tid < 64) {
        float m = -1e30f;
#pragma unroll 4
        for (int k = 0; k < 64; k++) m = fmaxf(m, sS[tid][k]);
        float ssum = 0.f;
#pragma unroll 4
        for (int k = 0; k < 64; k++) {
            float e = __expf(sS[tid][k] - m);
            sS[tid][k] = e;
            ssum += e;
        }
        float inv = 1.f / ssum;
#pragma unroll 4
        for (int k = 0; k < 64; k++) sS[tid][k] *= inv;
    }
    __syncthreads();
    float4 oacc[4];
#pragma unroll
    for (int j = 0; j < 4; j++) oacc[j] = make_float4(0.f, 0.f, 0.f, 0.f);
    for (int k = 0; k < 64; k++) {
        float wv = sS[qr][k];
#pragma unroll
        for (int j4 = 0; j4 < 4; j4++) {
            float4 vv = *(const float4*)&sV[k][c0 + j4 * 4];
            oacc[j4].x = fmaf(wv, vv.x, oacc[j4].x);
            oacc[j4].y = fmaf(wv, vv.y, oacc[j4].y);
            oacc[j4].z = fmaf(wv, vv.z, oacc[j4].z);
            oacc[j4].w = fmaf(wv, vv.w, oacc[j4].w);
        }
    }
    ushort* orow = o + ((size_t)b * 64 + qr) * DMODEL + h * 64 + c0;
#pragma unroll
    for (int j4 = 0; j4 < 4; j4++) {
        orow[j4 * 4 + 0] = f2b(oacc[j4].x);
        orow[j4 * 4 + 1] = f2b(oacc[j4].y);
        orow[j4 * 4 + 2] = f2b(oacc[j4].z);
        orow[j4 * 4 + 3] = f2b(oacc[j4].w);
    }
}

// ---------------- layernorm; residual = sum of nP fp32 slabs ----------------
__global__ __launch_bounds__(256) void ln_kernel(const float* __restrict__ x,
                                                 const float* __restrict__ rP, int nP, long rSlab,
                                                 const float* __restrict__ w,
                                                 const float* __restrict__ b,
                                                 float* __restrict__ out,
                                                 ushort* __restrict__ outbf) {
    __shared__ float scratch[4];
    int row = blockIdx.x, tid = threadIdx.x;
    const float* xr = x + (size_t)row * DMODEL;
    float v0 = xr[tid], v1 = xr[tid + 256], v2 = xr[tid + 512];
    for (int p = 0; p < nP; p++) {
        const float* rr = rP + (size_t)p * rSlab + (size_t)row * DMODEL;
        v0 += rr[tid]; v1 += rr[tid + 256]; v2 += rr[tid + 512];
    }
    float mean = block_reduce_sum(v0 + v1 + v2, scratch) * (1.f / DMODEL);
    float d0 = v0 - mean, d1 = v1 - mean, d2 = v2 - mean;
    float var = block_reduce_sum(d0 * d0 + d1 * d1 + d2 * d2, scratch) * (1.f / DMODEL);
    float inv = rsqrtf(var + 1e-5f);
    float o0 = d0 * inv * w[tid] + b[tid];
    float o1 = d1 * inv * w[tid + 256] + b[tid + 256];
    float o2 = d2 * inv * w[tid + 512] + b[tid + 512];
    float* orow = out + (size_t)row * DMODEL;
    orow[tid] = o0; orow[tid + 256] = o1; orow[tid + 512] = o2;
    if (outbf) {
        ushort* obf = outbf + (size_t)row * DMODEL;
        obf[tid] = f2b(o0); obf[tid + 256] = f2b(o1); obf[tid + 512] = f2b(o2);
    }
}

// ---------------- pad mask output ----------------
__global__ void mask_kernel(const int* __restrict__ n_segs, float* __restrict__ mout) {
    int i = threadIdx.x;
    int b = i >> 6, s = i & 63;
    mout[i] = (s >= n_segs[b]) ? 1.0f : 0.0f;
}

// ---------------- host ----------------
extern "C" void kernel_launch(void* const* d_in, const int* in_sizes, int n_in,
                              void* d_out, int out_size, void* d_ws, size_t ws_size,
                              hipStream_t stream) {
    const float* x = (const float*)d_in[0];
    const int* seg_bounds = (const int*)d_in[1];
    const int* n_segs = (const int*)d_in[2];
    const float* cw[7], * cb[7];
    for (int i = 0; i < 7; i++) { cw[i] = (const float*)d_in[3 + 2 * i]; cb[i] = (const float*)d_in[4 + 2 * i]; }
    const float* attn_v = (const float*)d_in[17];
    const float* pos_emb = (const float*)d_in[18];
    const float* in_w = (const float*)d_in[19];
    const float* in_b = (const float*)d_in[20];
    const float* out_w = (const float*)d_in[21];
    const float* out_b = (const float*)d_in[22];
    const float* ff1_w = (const float*)d_in[23];
    const float* ff1_b = (const float*)d_in[24];
    const float* ff2_w = (const float*)d_in[25];
    const float* ff2_b = (const float*)d_in[26];
    const float* ln1_w = (const float*)d_in[27];
    const float* ln1_b = (const float*)d_in[28];
    const float* ln2_w = (const float*)d_in[29];
    const float* ln2_b = (const float*)d_in[30];
    const float* fln_w = (const float*)d_in[31];
    const float* fln_b = (const float*)d_in[32];
    const float* proj_w = (const float*)d_in[33];
    const float* proj_b = (const float*)d_in[34];

    mask_kernel<<<1, 256, 0, stream>>>(n_segs, (float*)d_out + 256 * NCLS);

    size_t off = 0;
    auto alloc = [&](size_t bytes) {
        void* p = (char*)d_ws + off;
        off += (bytes + 255) & ~(size_t)255;
        return p;
    };
    // per-batch row strides (rows of 512 ic)
    const long c0S = 16001L * 512, o1S = 16000L * 512, o2S = 8000L * 512,
               o3S = 4000L * 512, o4S = 2000L * 512, o5S = 1000L * 512, fS = 499L * 768;
    ushort* wbc = (ushort*)alloc(4194304ULL * 2);              // 8.39 MB
    ushort* w0pad = (ushort*)alloc(512ULL * 32 * 2);
    ushort* c0_all = (ushort*)alloc((size_t)BATCH * c0S * 2);  // 65.5 MB
    ushort* o1 = (ushort*)alloc((size_t)BATCH * o1S * 2);      // 65.5 MB
    ushort* o2 = (ushort*)alloc((size_t)BATCH * o2S * 2);      // 32.8 MB
    ushort* o3 = (ushort*)alloc((size_t)BATCH * o3S * 2);      // 16.4 MB
    ushort* o4 = (ushort*)alloc((size_t)BATCH * o4S * 2);      // 8.2 MB
    ushort* o5 = (ushort*)alloc((size_t)BATCH * o5S * 2);      // 4.1 MB
    ushort* feats = (ushort*)alloc((size_t)BATCH * fS * 2);    // 3.07 MB
    float* scores = (float*)alloc((size_t)4 * TP_ * 4);
    float* tokens = (float*)alloc((size_t)256 * DMODEL * 4);
    ushort* tokens_bf = (ushort*)alloc((size_t)256 * DMODEL * 2);
    ushort* oall_bf = (ushort*)alloc((size_t)256 * DMODEL * 2);
    float* ybuf = (float*)alloc((size_t)256 * DMODEL * 4);
    ushort* ybf = (ushort*)alloc((size_t)256 * DMODEL * 2);
    if (off > ws_size) return;  // diagnostic bail

    // transformer-phase slabs alias c0_all (conv phase finished by then):
    // 9.44 + 6.29 + 6.29 + 1.05 = 23.1 MB <= 65.5 MB
    float* qkv_p = (float*)c0_all;                          // 4 x 256x2304
    float* ffh_p = qkv_p + (size_t)4 * 256 * 2304;          // 3 x 256x2048
    float* tmp_p = ffh_p + (size_t)3 * 256 * 2048;          // 8 x 256x768
    ushort* ffh_bf = (ushort*)(tmp_p + (size_t)8 * 256 * 768);

    ushort* wc1 = wbc, * wc2 = wbc + 786432, * wc3 = wbc + 1572864,
          * wc4 = wbc + 2359296, * wc5 = wbc + 2883584, * wc6 = wbc + 3407872;

    convw_kernel<<<dim3(512, 7), 256, 0, stream>>>(cw[1], cw[2], cw[3], cw[4], cw[5], cw[6],
                                                   cw[0], wbc, w0pad);

    // ---- conv stack, batch-merged via blockIdx.z (conv0/conv1 in two u-chunks) ----
    conv0_mfma<<<dim3(126, 4, BATCH), 256, 0, stream>>>(x, w0pad, cb[0], c0_all, 0, 16001, c0S);
    convT_mfma<3><<<dim3(63, 4, BATCH), 256, 0, stream>>>(
        c0_all, wc1, cb[1], o1, 512, 512, 15999, 0, 0, 16000, c0S, o1S);
    conv0_mfma<<<dim3(125, 4, BATCH), 256, 0, stream>>>(x, w0pad, cb[0], c0_all, 16000, 15999, c0S);
    convT_mfma<3><<<dim3(63, 4, BATCH), 256, 0, stream>>>(
        c0_all, wc1, cb[1], o1, 512, 512, 15999, 8000, 16000, 15998, c0S, o1S);
    convT_mfma<3><<<dim3(63, 4, BATCH), 256, 0, stream>>>(
        o1, wc2, cb[2], o2, 512, 512, 7999, 0, 0, 15998, o1S, o2S);
    convT_mfma<3><<<dim3(32, 4, BATCH), 256, 0, stream>>>(
        o2, wc3, cb[3], o3, 512, 512, 3999, 0, 0, 7998, o2S, o3S);
    convT_mfma<2><<<dim3(16, 4, BATCH), 256, 0, stream>>>(
        o3, wc4, cb[4], o4, 512, 512, 1999, 0, 0, 3998, o3S, o4S);
    convT_mfma<2><<<dim3(8, 4, BATCH), 256, 0, stream>>>(
        o4, wc5, cb[5], o5, 512, 512, 999, 0, 0, 1998, o4S, o5S);
    convT_mfma<2><<<dim3(4, 6, BATCH), 256, 0, stream>>>(
        o5, wc6, cb[6], feats, 512, 768, 499, 0, 0, 998, o5S, fS);

    // ---- pooling ----
    scores_kernel<<<dim3(125, 4), 256, 0, stream>>>(feats, attn_v, scores);
    pool_kernel<<<dim3(SMAX_, 4), 256, 0, stream>>>(feats, scores, seg_bounds, n_segs,
                                                    pos_emb, tokens, tokens_bf);

    // ---- transformer (split-K GEMMs, 256-row tile + 2-phase prefetch) ----
    const long qkvSlab = (long)256 * 2304;
    const long tmpSlab = (long)256 * 768;
    const long ffhSlab = (long)256 * 2048;
    for (int l = 0; l < NLAYER; l++) {
        const float* iw = in_w + (size_t)l * 2304 * DMODEL;
        const float* ib = in_b + (size_t)l * 2304;
        const float* ow = out_w + (size_t)l * DMODEL * DMODEL;
        const float* ob = out_b + (size_t)l * DMODEL;
        const float* f1w = ff1_w + (size_t)l * FFDIM * DMODEL;
        const float* f1b = ff1_b + (size_t)l * FFDIM;
        const float* f2w = ff2_w + (size_t)l * DMODEL * FFDIM;
        const float* f2b_ = ff2_b + (size_t)l * DMODEL;

        gemm_sk2<<<dim3(1, 18, 4), 256, 0, stream>>>(tokens_bf, iw, ib, qkv_p, 2304, 768, 192, qkvSlab);
        attn_kernel<<<dim3(12, 4), 256, 0, stream>>>(qkv_p, n_segs, oall_bf, qkvSlab, 4);
        gemm_sk2<<<dim3(1, 6, 4), 256, 0, stream>>>(oall_bf, ow, ob, tmp_p, 768, 768, 192, tmpSlab);
        ln_kernel<<<256, 256, 0, stream>>>(tokens, tmp_p, 4, tmpSlab,
                                           ln1_w + l * DMODEL, ln1_b + l * DMODEL, tokens, tokens_bf);
        gemm_sk2<<<dim3(1, 16, 3), 256, 0, stream>>>(tokens_bf, f1w, f1b, ffh_p, 2048, 768, 256, ffhSlab);
        relu_cast<<<512, 256, 0, stream>>>(ffh_p, ffh_bf, (long)256 * 2048, ffhSlab, 3);
        gemm_sk2<<<dim3(1, 6, 8), 256, 0, stream>>>(ffh_bf, f2w, f2b_, tmp_p, 768, 2048, 256, tmpSlab);
        ln_kernel<<<256, 256, 0, stream>>>(tokens, tmp_p, 8, tmpSlab,
                                           ln2_w + l * DMODEL, ln2_b + l * DMODEL, tokens, tokens_bf);
    }

    // ---- head ----
    ln_kernel<<<256, 256, 0, stream>>>(tokens, nullptr, 0, 0, fln_w, fln_b, ybuf, ybf);
    conv_mfma<1, 1, 0, 0, 1><<<dim3(2, 1, 1), 256, 0, stream>>>(
        ybf, nullptr, proj_w, proj_b, (float*)d_out, 768, NCLS, 256, 0, 0, 0, 0);
}

// Round 3
// 2284.780 us; speedup vs baseline: 1.1205x; 1.0238x over previous
//
#include <hip/hip_runtime.h>
#include <hip/hip_bf16.h>

// ---------------- constants ----------------
#define BATCH 4
#define TIN0 160000
#define DMODEL 768
#define NLAYER 12
#define FFDIM 2048
#define NCLS 100
#define SMAX_ 64
#define TP_ 499

typedef __attribute__((ext_vector_type(8))) short short8;
typedef __attribute__((ext_vector_type(4))) float f32x4;

__device__ inline ushort f2b(float f) { __hip_bfloat16 h = __float2bfloat16(f); return *(ushort*)&h; }
__device__ inline float b2f(ushort u) { __hip_bfloat16 h = *(__hip_bfloat16*)&u; return __bfloat162float(h); }

__device__ inline void gl_lds16(const ushort* g, ushort* l) {
    __builtin_amdgcn_global_load_lds((const __attribute__((address_space(1))) unsigned int*)g,
                                     (__attribute__((address_space(3))) unsigned int*)l, 16, 0, 0);
}

// ---------------- reduction helpers ----------------
__device__ inline float wave_reduce_sum(float v) {
#pragma unroll
    for (int off = 32; off > 0; off >>= 1) v += __shfl_down(v, off, 64);
    return v;
}
__device__ inline float wave_reduce_max(float v) {
#pragma unroll
    for (int off = 32; off > 0; off >>= 1) v = fmaxf(v, __shfl_down(v, off, 64));
    return v;
}
__device__ inline float block_reduce_sum(float v, float* scratch) {
    v = wave_reduce_sum(v);
    int wid = threadIdx.x >> 6;
    if ((threadIdx.x & 63) == 0) scratch[wid] = v;
    __syncthreads();
    float r = scratch[0] + scratch[1] + scratch[2] + scratch[3];
    __syncthreads();
    return r;
}
__device__ inline float block_reduce_max(float v, float* scratch) {
    v = wave_reduce_max(v);
    int wid = threadIdx.x >> 6;
    if ((threadIdx.x & 63) == 0) scratch[wid] = v;
    __syncthreads();
    float r = fmaxf(fmaxf(scratch[0], scratch[1]), fmaxf(scratch[2], scratch[3]));
    __syncthreads();
    return r;
}

// =================================================================
// Conv MFMA, kw-inner. XCD-aware swizzle: total blocks % 8 == 0 and
// blocksPerXcd % NOC == 0 required (grids padded by host). All oc-tiles
// of a (t,z) pair land on the SAME XCD, pairs contiguous per XCD ->
// A-tile fetched from HBM once per XCD + halo reuse between t-tiles.
// Padded t-tiles: staging clamps u (valid reads), epilogue t<Tout guard.
// =================================================================
template <int KW>
__global__ __launch_bounds__(256) void convT_mfma(
    const ushort* __restrict__ A,
    const ushort* __restrict__ Wc,
    const float* __restrict__ bias,
    ushort* __restrict__ outp,
    int Cin, int Cout, int Tout,
    int tBase, int uBase, int uMax,
    long aStride, long oStride) {
    constexpr int EB = 132;            // even-row region (rows)
    __shared__ ushort sA[288 * 64];    // 36.9 KB
    __shared__ ushort sB[KW * 128 * 32];
    const int tid = threadIdx.x;
    const int lane = tid & 63;
    const int wv = tid >> 6;
    const int mrow = lane & 15;
    const int kq = lane >> 4;

    // ---- XCD swizzle (bijective remap of flat block id) ----
    const int NT = gridDim.x, NOC = gridDim.y;
    int tIdx = blockIdx.x, ocIdx = blockIdx.y, zIdx = blockIdx.z;
    {
        int total = NT * NOC * (int)gridDim.z;
        int perx = total >> 3;
        if ((total & 7) == 0 && (perx % NOC) == 0) {
            int f = blockIdx.x + NT * (blockIdx.y + NOC * blockIdx.z);
            int a = f & 7, b = f >> 3;
            int oc = b % NOC, jp = b / NOC;
            int p = a * (perx / NOC) + jp;   // (t,z) pair, chunked per XCD
            tIdx = p % NT; zIdx = p / NT; ocIdx = oc;
        }
    }
    const int t0 = tBase + tIdx * 128;
    const int oc0 = ocIdx * 128;
    const ushort* Ab = A + (size_t)zIdx * aStride;
    ushort* outb = outp + (size_t)zIdx * oStride;
    const int K = KW * Cin;

    f32x4 acc[2][8];
#pragma unroll
    for (int s = 0; s < 2; s++)
#pragma unroll
        for (int n = 0; n < 8; n++) acc[s][n] = (f32x4){0.f, 0.f, 0.f, 0.f};

    const int nC8 = Cin >> 6;
    for (int c8 = 0; c8 < nC8; c8++) {
        const int ic0 = c8 << 6;
        // ---- stage A (even rows 0..131, odd rows 132..259; 288 padded) ----
#pragma unroll
        for (int rd = 0; rd < 9; rd++) {
            int slotBase = rd * 256 + wv * 64;
            int slot = slotBase + lane;
            int r = slot >> 3;
            int g = (slot & 7) ^ (r & 7);
            int u = (r < EB) ? (2 * t0 + 2 * r) : (2 * t0 + 2 * (r - EB) + 1);
            u -= uBase;
            if (u < 0) u = 0;
            if (u > uMax) u = uMax;
            gl_lds16(Ab + (size_t)u * Cin + ic0 + g * 8, &sA[slotBase * 8]);
        }
#pragma unroll
        for (int h = 0; h < 2; h++) {
            // ---- stage B for this 32-k half ----
#pragma unroll
            for (int rd = 0; rd < KW * 2; rd++) {
                int slotBase = rd * 256 + wv * 64;
                int slot = slotBase + lane;
                int r = slot >> 2;
                int g = (slot & 3) ^ ((r >> 1) & 3);
                int ocr = oc0 + (r & 127);
                if (ocr > Cout - 1) ocr = Cout - 1;
                int kwi = r >> 7;
                gl_lds16(Wc + (size_t)ocr * K + kwi * Cin + ic0 + h * 32 + g * 8,
                         &sB[slotBase * 8]);
            }
            __syncthreads();
#pragma unroll
            for (int kw = 0; kw < KW; kw++) {
                const int abase = (kw & 1) ? EB : 0;
                const int aoff = kw >> 1;
#pragma unroll
                for (int s = 0; s < 2; s++) {
                    int ar = abase + wv * 32 + s * 16 + mrow + aoff;
                    short8 af = *(const short8*)&sA[ar * 64 + (((h * 4 + kq) ^ (ar & 7)) * 8)];
#pragma unroll
                    for (int n = 0; n < 8; n++) {
                        int br = kw * 128 + n * 16 + mrow;
                        short8 bf = *(const short8*)&sB[br * 32 + ((kq ^ ((br >> 1) & 3)) * 8)];
                        acc[s][n] = __builtin_amdgcn_mfma_f32_16x16x32_bf16(af, bf, acc[s][n], 0, 0, 0);
                    }
                }
            }
            __syncthreads();
        }
    }

    // ---- epilogue (verified C-layout: row=kq*4+r -> t, col=mrow -> oc) ----
    float bz[8];
#pragma unroll
    for (int n = 0; n < 8; n++) {
        int oc = oc0 + n * 16 + mrow;
        bz[n] = (oc < Cout) ? bias[oc] : 0.f;
    }
#pragma unroll
    for (int s = 0; s < 2; s++) {
        int tb = t0 + wv * 32 + s * 16 + kq * 4;
#pragma unroll
        for (int n = 0; n < 8; n++) {
            int oc = oc0 + n * 16 + mrow;
            if (oc >= Cout) continue;
#pragma unroll
            for (int r = 0; r < 4; r++) {
                int t = tb + r;
                if (t < Tout) outb[(size_t)t * Cout + oc] = f2b(fmaxf(acc[s][n][r] + bz[n], 0.f));
            }
        }
    }
}

// =================================================================
// Generic MFMA GEMM (head projection only), BF32 weight path.
// =================================================================
template <int KW, int STRIDE, int RELU, int OBF, int BF32>
__global__ __launch_bounds__(256) void conv_mfma(
    const ushort* __restrict__ A,
    const ushort* __restrict__ Wc,
    const float* __restrict__ Wf,
    const float* __restrict__ bias,
    void* __restrict__ outv,
    int Cin, int Cout, int Tout, int tBase, int uBase,
    long aStride, long oStride) {
    const int K = KW * Cin;
    const int nCh = K >> 5;
    const int t0 = tBase + blockIdx.x * 128;
    const int oc0 = blockIdx.y * 128;
    const int b = blockIdx.z;
    const ushort* Ab = A + (size_t)b * aStride;
    __shared__ ushort sA[4096];
    __shared__ ushort sB[4096];
    const int tid = threadIdx.x;
    const int lane = tid & 63;
    const int wv = tid >> 6;
    const int rsub = lane >> 2;
    const int kgW = (lane & 3) ^ ((lane >> 3) & 3);
    const int mrow = lane & 15;
    const int kq = lane >> 4;
    const int slot8 = (mrow * 4 + (kq ^ ((mrow >> 1) & 3))) * 8;

    f32x4 acc[2][8];
#pragma unroll
    for (int s = 0; s < 2; s++)
#pragma unroll
        for (int n = 0; n < 8; n++) acc[s][n] = (f32x4){0.f, 0.f, 0.f, 0.f};

    for (int c = 0; c < nCh; c++) {
#pragma unroll
        for (int j = 0; j < 2; j++) {
            int t = t0 + j * 64 + wv * 16 + rsub;
            if (t > Tout - 1) t = Tout - 1;
            int u = STRIDE * t - uBase;
            gl_lds16(Ab + (size_t)u * Cin + c * 32 + kgW * 8, &sA[(j * 64 + wv * 16) * 32]);
        }
#pragma unroll
        for (int j = 0; j < 2; j++) {
            int rowb = oc0 + j * 64 + wv * 16 + rsub;
            if (rowb > Cout - 1) rowb = Cout - 1;
            if (BF32) {
                const float* wp = Wf + (size_t)rowb * K + c * 32 + kgW * 8;
                float4 w0_ = *(const float4*)wp;
                float4 w1_ = *(const float4*)(wp + 4);
                short8 vals;
                vals[0] = (short)f2b(w0_.x); vals[1] = (short)f2b(w0_.y);
                vals[2] = (short)f2b(w0_.z); vals[3] = (short)f2b(w0_.w);
                vals[4] = (short)f2b(w1_.x); vals[5] = (short)f2b(w1_.y);
                vals[6] = (short)f2b(w1_.z); vals[7] = (short)f2b(w1_.w);
                *(short8*)&sB[(j * 64 + wv * 16) * 32 + lane * 8] = vals;
            } else {
                gl_lds16(Wc + (size_t)rowb * K + c * 32 + kgW * 8, &sB[(j * 64 + wv * 16) * 32]);
            }
        }
        __syncthreads();
        short8 a0 = *(const short8*)&sA[(wv * 32 + 0) * 32 + slot8];
        short8 a1 = *(const short8*)&sA[(wv * 32 + 16) * 32 + slot8];
#pragma unroll
        for (int n = 0; n < 8; n++) {
            short8 bf = *(const short8*)&sB[(n * 16) * 32 + slot8];
            acc[0][n] = __builtin_amdgcn_mfma_f32_16x16x32_bf16(a0, bf, acc[0][n], 0, 0, 0);
            acc[1][n] = __builtin_amdgcn_mfma_f32_16x16x32_bf16(a1, bf, acc[1][n], 0, 0, 0);
        }
        __syncthreads();
    }
    float* outf = (float*)outv + (size_t)b * oStride;
    ushort* outh = (ushort*)outv + (size_t)b * oStride;
    float bz[8];
#pragma unroll
    for (int n = 0; n < 8; n++) {
        int oc = oc0 + n * 16 + mrow;
        bz[n] = (oc < Cout) ? bias[oc] : 0.f;
    }
#pragma unroll
    for (int s = 0; s < 2; s++) {
        int tb = t0 + wv * 32 + s * 16 + kq * 4;
#pragma unroll
        for (int n = 0; n < 8; n++) {
            int oc = oc0 + n * 16 + mrow;
            if (oc >= Cout) continue;
#pragma unroll
            for (int r = 0; r < 4; r++) {
                int t = tb + r;
                if (t < Tout) {
                    float v = acc[s][n][r] + bz[n];
                    if (RELU) v = fmaxf(v, 0.f);
                    if (OBF) outh[(size_t)t * Cout + oc] = f2b(v);
                    else outf[(size_t)t * Cout + oc] = v;
                }
            }
        }
    }
}

// =================================================================
// Split-K GEMM v3 (transformer): 256-row tile, 64-wide K-step in two
// 32-k halves, double-buffered 2-phase prefetch. Halves the barrier/
// drain count vs 32-k chunks. A bf16 [256][K], W fp32 [M][K] -> fp32
// partial slabs outp[kc*oSlab + t*M + oc]; kc==0 slab carries bias.
// KCH must be a multiple of 64.
// =================================================================
__global__ __launch_bounds__(256) void gemm_sk64(
    const ushort* __restrict__ A, const float* __restrict__ Wf,
    const float* __restrict__ bias, float* __restrict__ outp,
    int M, int K, int KCH, long oSlab) {
    __shared__ ushort sA[2][2][8192];   // [buf][half] 256 rows x 32 k -> 64 KB
    __shared__ ushort sB[2][2][4096];   // [buf][half] 128 rows x 32 k -> 32 KB
    const int tid = threadIdx.x;
    const int lane = tid & 63;
    const int wv = tid >> 6;
    const int rsub = lane >> 2;
    const int kgW = (lane & 3) ^ ((lane >> 3) & 3);
    const int mrow = lane & 15;
    const int kq = lane >> 4;
    const int slot8 = (mrow * 4 + (kq ^ ((mrow >> 1) & 3))) * 8;
    const int oc0 = blockIdx.y * 128;
    const int kc = blockIdx.z;
    const int k0 = kc * KCH;
    const int nIt = KCH >> 6;

    f32x4 acc[4][8];
#pragma unroll
    for (int s = 0; s < 4; s++)
#pragma unroll
        for (int n = 0; n < 8; n++) acc[s][n] = (f32x4){0.f, 0.f, 0.f, 0.f};

    float4 wr[2][2][2];   // [half][j][lo/hi]

    auto stageA = [&](int buf, int half, int kk) {
#pragma unroll
        for (int j = 0; j < 4; j++) {
            int t = j * 64 + wv * 16 + rsub;
            gl_lds16(A + (size_t)t * K + kk + kgW * 8, &sA[buf][half][(j * 64 + wv * 16) * 32]);
        }
    };
    auto wload = [&](int kk) {
#pragma unroll
        for (int h = 0; h < 2; h++)
#pragma unroll
            for (int j = 0; j < 2; j++) {
                int rowb = oc0 + j * 64 + wv * 16 + rsub;
                const float* wp = Wf + (size_t)rowb * K + kk + h * 32 + kgW * 8;
                wr[h][j][0] = *(const float4*)wp;
                wr[h][j][1] = *(const float4*)(wp + 4);
            }
    };
    auto wstore = [&](int buf) {
#pragma unroll
        for (int h = 0; h < 2; h++)
#pragma unroll
            for (int j = 0; j < 2; j++) {
                short8 vals;
                vals[0] = (short)f2b(wr[h][j][0].x); vals[1] = (short)f2b(wr[h][j][0].y);
                vals[2] = (short)f2b(wr[h][j][0].z); vals[3] = (short)f2b(wr[h][j][0].w);
                vals[4] = (short)f2b(wr[h][j][1].x); vals[5] = (short)f2b(wr[h][j][1].y);
                vals[6] = (short)f2b(wr[h][j][1].z); vals[7] = (short)f2b(wr[h][j][1].w);
                *(short8*)&sB[buf][h][(j * 64 + wv * 16) * 32 + lane * 8] = vals;
            }
    };

    // prologue: stage chunk 0 into buffer 0
    stageA(0, 0, k0);
    stageA(0, 1, k0 + 32);
    wload(k0);
    wstore(0);
    __syncthreads();   // drains vmcnt+lgkm -> buf0 ready

    for (int c = 0; c < nIt; c++) {
        const int cur = c & 1;
        const int nxt = cur ^ 1;
        if (c + 1 < nIt) {
            int kn = k0 + ((c + 1) << 6);
            stageA(nxt, 0, kn);        // async A -> other LDS buffer
            stageA(nxt, 1, kn + 32);
            wload(kn);                 // W fp32 -> regs (in flight)
        }
#pragma unroll
        for (int h = 0; h < 2; h++) {
            short8 a0 = *(const short8*)&sA[cur][h][(wv * 64 + 0) * 32 + slot8];
            short8 a1 = *(const short8*)&sA[cur][h][(wv * 64 + 16) * 32 + slot8];
            short8 a2 = *(const short8*)&sA[cur][h][(wv * 64 + 32) * 32 + slot8];
            short8 a3 = *(const short8*)&sA[cur][h][(wv * 64 + 48) * 32 + slot8];
#pragma unroll
            for (int n = 0; n < 8; n++) {
                short8 bf = *(const short8*)&sB[cur][h][(n * 16) * 32 + slot8];
                acc[0][n] = __builtin_amdgcn_mfma_f32_16x16x32_bf16(a0, bf, acc[0][n], 0, 0, 0);
                acc[1][n] = __builtin_amdgcn_mfma_f32_16x16x32_bf16(a1, bf, acc[1][n], 0, 0, 0);
                acc[2][n] = __builtin_amdgcn_mfma_f32_16x16x32_bf16(a2, bf, acc[2][n], 0, 0, 0);
                acc[3][n] = __builtin_amdgcn_mfma_f32_16x16x32_bf16(a3, bf, acc[3][n], 0, 0, 0);
            }
        }
        if (c + 1 < nIt) wstore(nxt);   // regs arrived during MFMA; ds_write other buffer
        __syncthreads();                // drain: A(next)+B(next) landed
    }

    float* op = outp + (size_t)kc * oSlab;
#pragma unroll
    for (int s = 0; s < 4; s++) {
        int tb = wv * 64 + s * 16 + kq * 4;
#pragma unroll
        for (int n = 0; n < 8; n++) {
            int oc = oc0 + n * 16 + mrow;
            float bz = (kc == 0) ? bias[oc] : 0.f;
#pragma unroll
            for (int r = 0; r < 4; r++) {
                op[(size_t)(tb + r) * M + oc] = acc[s][n][r] + bz;
            }
        }
    }
}

// ---------------- relu(sum of nP slabs) -> bf16 ----------------
__global__ __launch_bounds__(256) void relu_cast(const float* __restrict__ p,
                                                 ushort* __restrict__ o,
                                                 long n, long slab, int nP) {
    for (long i = (long)blockIdx.x * 1024 + threadIdx.x; i < n; i += (long)gridDim.x * 1024) {
#pragma unroll
        for (int j = 0; j < 4; j++) {
            long k = i + (long)j * 256;
            if (k < n) {
                float v = 0.f;
                for (int q = 0; q < nP; q++) v += p[k + q * slab];
                o[k] = f2b(fmaxf(v, 0.f));
            }
        }
    }
}

// =================================================================
// conv0 as MFMA GEMM (batch-merged via blockIdx.z)
// =================================================================
__global__ __launch_bounds__(256) void conv0_mfma(const float* __restrict__ x,
                                                  const ushort* __restrict__ w0pad,
                                                  const float* __restrict__ b0,
                                                  ushort* __restrict__ c0,
                                                  int uBase, int nU, long oStride) {
    __shared__ ushort sA[4096];
    __shared__ ushort sB[4096];
    const int tid = threadIdx.x;
    const int lane = tid & 63;
    const int wv = tid >> 6;
    const int rsub = lane >> 2;
    const int kgW = (lane & 3) ^ ((lane >> 3) & 3);
    const int mrow = lane & 15;
    const int kq = lane >> 4;
    const int slot8 = (mrow * 4 + (kq ^ ((mrow >> 1) & 3))) * 8;
    const int r0 = blockIdx.x * 128;
    const int oc0 = blockIdx.y * 128;
    const float* xb = x + (size_t)blockIdx.z * TIN0;
    ushort* ob = c0 + (size_t)blockIdx.z * oStride;

    f32x4 acc[2][8];
#pragma unroll
    for (int s = 0; s < 2; s++)
#pragma unroll
        for (int n = 0; n < 8; n++) acc[s][n] = (f32x4){0.f, 0.f, 0.f, 0.f};

#pragma unroll
    for (int j = 0; j < 2; j++) {
        int r = r0 + j * 64 + wv * 16 + rsub;
        if (r > nU - 1) r = nU - 1;
        const float* xp = xb + (size_t)5 * (uBase + r);
        short8 vals = (short8){0, 0, 0, 0, 0, 0, 0, 0};
        if (kgW == 0) {
#pragma unroll
            for (int q = 0; q < 8; q++) vals[q] = (short)f2b(xp[q]);
        } else if (kgW == 1) {
            vals[0] = (short)f2b(xp[8]);
            vals[1] = (short)f2b(xp[9]);
        }
        *(short8*)&sA[(j * 64 + wv * 16) * 32 + lane * 8] = vals;
    }
#pragma unroll
    for (int j = 0; j < 2; j++) {
        int rowb = oc0 + j * 64 + wv * 16 + rsub;
        gl_lds16(w0pad + (size_t)rowb * 32 + kgW * 8, &sB[(j * 64 + wv * 16) * 32]);
    }
    __syncthreads();
    short8 a0 = *(const short8*)&sA[(wv * 32 + 0) * 32 + slot8];
    short8 a1 = *(const short8*)&sA[(wv * 32 + 16) * 32 + slot8];
#pragma unroll
    for (int n = 0; n < 8; n++) {
        short8 bf = *(const short8*)&sB[(n * 16) * 32 + slot8];
        acc[0][n] = __builtin_amdgcn_mfma_f32_16x16x32_bf16(a0, bf, acc[0][n], 0, 0, 0);
        acc[1][n] = __builtin_amdgcn_mfma_f32_16x16x32_bf16(a1, bf, acc[1][n], 0, 0, 0);
    }
#pragma unroll
    for (int s = 0; s < 2; s++) {
        int rb = r0 + wv * 32 + s * 16 + kq * 4;
#pragma unroll
        for (int n = 0; n < 8; n++) {
            int oc = oc0 + n * 16 + mrow;
            float bz = b0[oc];
#pragma unroll
            for (int r = 0; r < 4; r++) {
                int rr = rb + r;
                if (rr < nU) ob[(size_t)rr * 512 + oc] = f2b(fmaxf(acc[s][n][r] + bz, 0.f));
            }
        }
    }
}

// ---------------- conv-weight permute+cast ----------------
__global__ __launch_bounds__(256) void convw_kernel(
    const float* __restrict__ w1, const float* __restrict__ w2, const float* __restrict__ w3,
    const float* __restrict__ w4, const float* __restrict__ w5, const float* __restrict__ w6,
    const float* __restrict__ w0, ushort* __restrict__ dst, ushort* __restrict__ dw0) {
    const int z = blockIdx.y;
    const int COUTS[6] = {512, 512, 512, 512, 512, 768};
    const int KWS[6] = {3, 3, 3, 2, 2, 2};
    const long OFFS[6] = {0, 786432, 1572864, 2359296, 2883584, 3407872};
    const float* srcs[6] = {w1, w2, w3, w4, w5, w6};
    if (z == 6) {
        for (int o = blockIdx.x * 256 + threadIdx.x; o < 512 * 32; o += gridDim.x * 256) {
            int oc = o >> 5, q = o & 31;
            dw0[o] = (q < 10) ? f2b(w0[oc * 10 + q]) : (ushort)0;
        }
        return;
    }
    const float* src = srcs[z];
    ushort* d = dst + OFFS[z];
    const int Cin = 512, Kw = KWS[z];
    const int K = Cin * Kw;
    const long n = (long)COUTS[z] * K;
    for (long o = blockIdx.x * 256 + threadIdx.x; o < n; o += (long)gridDim.x * 256) {
        long oc = o / K;
        int rem = (int)(o - oc * K);
        int kw = rem / Cin, ic = rem - kw * Cin;
        d[o] = f2b(src[(oc * Cin + ic) * Kw + kw]);
    }
}

// ---------------- scores ----------------
__global__ __launch_bounds__(256) void scores_kernel(const ushort* __restrict__ feats,
                                                     const float* __restrict__ v,
                                                     float* __restrict__ scores) {
    int b = blockIdx.y;
    int t = blockIdx.x * 4 + (threadIdx.x >> 6);
    if (t >= TP_) return;
    int lane = threadIdx.x & 63;
    const ushort* f = feats + ((size_t)b * TP_ + t) * DMODEL + lane * 12;
    float acc = 0.f;
#pragma unroll
    for (int q = 0; q < 12; q++) acc = fmaf(b2f(f[q]), v[lane * 12 + q], acc);
    acc = wave_reduce_sum(acc);
    if (lane == 0) scores[b * TP_ + t] = acc;
}

// ---------------- per-segment softmax pooling + pos_emb ----------------
__global__ __launch_bounds__(256) void pool_kernel(const ushort* __restrict__ featsAll,
                                                   const float* __restrict__ scoresAll,
                                                   const int* __restrict__ seg_bounds,
                                                   const int* __restrict__ n_segs,
                                                   const float* __restrict__ pos_emb,
                                                   float* __restrict__ tokens,
                                                   ushort* __restrict__ tokens_bf) {
    __shared__ float scratch[4];
    __shared__ float wgt[512];
    int s = blockIdx.x, b = blockIdx.y, tid = threadIdx.x;
    float* tout = tokens + ((size_t)b * SMAX_ + s) * DMODEL;
    ushort* tbf = tokens_bf + ((size_t)b * SMAX_ + s) * DMODEL;
    int ns = n_segs[b];
    if (s >= ns) {
        for (int c = tid; c < DMODEL; c += 256) {
            float v = pos_emb[s * DMODEL + c];
            tout[c] = v; tbf[c] = f2b(v);
        }
        return;
    }
    const float* sc = scoresAll + b * TP_;
    int b0 = seg_bounds[b * (SMAX_ + 1) + s];
    int b1 = seg_bounds[b * (SMAX_ + 1) + s + 1];
    int st = min(max(b0, 0), TP_ - 1);
    int en = max(st + 1, min(max(b1, 0), TP_));
    float lm = -1e30f;
    for (int t = st + tid; t < en; t += 256) lm = fmaxf(lm, sc[t]);
    float m = block_reduce_max(lm, scratch);
    float ls = 0.f;
    for (int t = st + tid; t < en; t += 256) ls += __expf(sc[t] - m);
    float den = block_reduce_sum(ls, scratch);
    float inv = 1.f / den;
    for (int t = st + tid; t < en; t += 256) wgt[t - st] = __expf(sc[t] - m) * inv;
    __syncthreads();
    int len = en - st;
    const ushort* f = featsAll + ((size_t)b * TP_ + st) * DMODEL;
    float a0 = 0.f, a1 = 0.f, a2 = 0.f;
    for (int t = 0; t < len; t++) {
        float wv = wgt[t];
        const ushort* fr = f + (size_t)t * DMODEL;
        a0 = fmaf(wv, b2f(fr[tid]), a0);
        a1 = fmaf(wv, b2f(fr[tid + 256]), a1);
        a2 = fmaf(wv, b2f(fr[tid + 512]), a2);
    }
    float v0 = a0 + pos_emb[s * DMODEL + tid];
    float v1 = a1 + pos_emb[s * DMODEL + tid + 256];
    float v2 = a2 + pos_emb[s * DMODEL + tid + 512];
    tout[tid] = v0; tout[tid + 256] = v1; tout[tid + 512] = v2;
    tbf[tid] = f2b(v0); tbf[tid + 256] = f2b(v1); tbf[tid + 512] = f2b(v2);
}

// ---------------- attention: qkv from nP fp32 partial slabs ----------------
__global__ __launch_bounds__(256) void attn_kernel(const float* __restrict__ qkv_p,
                                                   const int* __restrict__ n_segs,
                                                   ushort* __restrict__ o, long slab, int nP) {
    __shared__ float sK[64][68];
    __shared__ float sV[64][68];
    __shared__ float sS[64][68];
    int h = blockIdx.x, b = blockIdx.y, tid = threadIdx.x;
    int ns = n_segs[b];
    const float* base = qkv_p + (size_t)b * 64 * 2304 + h * 64;
    for (int idx = tid; idx < 4096; idx += 256) {
        int s_ = idx >> 6, d = idx & 63;
        size_t kofs = (size_t)s_ * 2304 + 768 + d;
        size_t vofs = (size_t)s_ * 2304 + 1536 + d;
        float kv = 0.f, vv = 0.f;
        for (int p = 0; p < nP; p++) { kv += base[kofs + p * slab]; vv += base[vofs + p * slab]; }
        sK[s_][d] = kv; sV[s_][d] = vv;
    }
    __syncthreads();
    int qr = tid >> 2;
    int c0 = (tid & 3) * 16;
    const float* qrow = base + (size_t)qr * 2304;
    float acc[16];
#pragma unroll
    for (int j = 0; j < 16; j++) acc[j] = 0.f;
    for (int d = 0; d < 64; d += 4) {
        float4 qv = make_float4(0.f, 0.f, 0.f, 0.f);
        for (int p = 0; p < nP; p++) {
            float4 qp = *(const float4*)(qrow + p * slab + d);
            qv.x += qp.x; qv.y += qp.y; qv.z += qp.z; qv.w += qp.w;
        }
#pragma unroll
        for (int j = 0; j < 16; j++) {
            float4 kv = *(const float4*)&sK[c0 + j][d];
            acc[j] += qv.x * kv.x + qv.y * kv.y + qv.z * kv.z + qv.w * kv.w;
        }
    }
#pragma unroll
    for (int j = 0; j < 16; j++) {
        int kc = c0 + j;
        float vv = acc[j] * 0.125f;
        if (kc >= ns) vv = -1e9f;
        sS[qr][kc] = vv;
    }
    __syncthreads();
    if (tid < 64) {
        float m = -1e30f;
#pragma unroll 4
        for (int k = 0; k < 64; k++) m = fmaxf(m, sS[tid][k]);
        float ssum = 0.f;
#pragma unroll 4
        for (int k = 0; k < 64; k++) {
            float e = __expf(sS[tid][k] - m);
            sS[tid][k] = e;
            ssum += e;
        }
        float inv = 1.f / ssum;
#pragma unroll 4
        for (int k = 0; k < 64; k++) sS[tid][k] *= inv;
    }
    __syncthreads();
    float4 oacc[4];
#pragma unroll
    for (int j = 0; j < 4; j++) oacc[j] = make_float4(0.f, 0.f, 0.f, 0.f);
    for (int k = 0; k < 64; k++) {
        float wv = sS[qr][k];
#pragma unroll
        for (int j4 = 0; j4 < 4; j4++) {
            float4 vv = *(const float4*)&sV[k][c0 + j4 * 4];
            oacc[j4].x = fmaf(wv, vv.x, oacc[j4].x);
            oacc[j4].y = fmaf(wv, vv.y, oacc[j4].y);
            oacc[j4].z = fmaf(wv, vv.z, oacc[j4].z);
            oacc[j4].w = fmaf(wv, vv.w, oacc[j4].w);
        }
    }
    ushort* orow = o + ((size_t)b * 64 + qr) * DMODEL + h * 64 + c0;
#pragma unroll
    for (int j4 = 0; j4 < 4; j4++) {
        orow[j4 * 4 + 0] = f2b(oacc[j4].x);
        orow[j4 * 4 + 1] = f2b(oacc[j4].y);
        orow[j4 * 4 + 2] = f2b(oacc[j4].z);
        orow[j4 * 4 + 3] = f2b(oacc[j4].w);
    }
}

// ---------------- layernorm; residual = sum of nP fp32 slabs ----------------
__global__ __launch_bounds__(256) void ln_kernel(const float* __restrict__ x,
                                                 const float* __restrict__ rP, int nP, long rSlab,
                                                 const float* __restrict__ w,
                                                 const float* __restrict__ b,
                                                 float* __restrict__ out,
                                                 ushort* __restrict__ outbf) {
    __shared__ float scratch[4];
    int row = blockIdx.x, tid = threadIdx.x;
    const float* xr = x + (size_t)row * DMODEL;
    float v0 = xr[tid], v1 = xr[tid + 256], v2 = xr[tid + 512];
    for (int p = 0; p < nP; p++) {
        const float* rr = rP + (size_t)p * rSlab + (size_t)row * DMODEL;
        v0 += rr[tid]; v1 += rr[tid + 256]; v2 += rr[tid + 512];
    }
    float mean = block_reduce_sum(v0 + v1 + v2, scratch) * (1.f / DMODEL);
    float d0 = v0 - mean, d1 = v1 - mean, d2 = v2 - mean;
    float var = block_reduce_sum(d0 * d0 + d1 * d1 + d2 * d2, scratch) * (1.f / DMODEL);
    float inv = rsqrtf(var + 1e-5f);
    float o0 = d0 * inv * w[tid] + b[tid];
    float o1 = d1 * inv * w[tid + 256] + b[tid + 256];
    float o2 = d2 * inv * w[tid + 512] + b[tid + 512];
    float* orow = out + (size_t)row * DMODEL;
    orow[tid] = o0; orow[tid + 256] = o1; orow[tid + 512] = o2;
    if (outbf) {
        ushort* obf = outbf + (size_t)row * DMODEL;
        obf[tid] = f2b(o0); obf[tid + 256] = f2b(o1); obf[tid + 512] = f2b(o2);
    }
}

// ---------------- pad mask output ----------------
__global__ void mask_kernel(const int* __restrict__ n_segs, float* __restrict__ mout) {
    int i = threadIdx.x;
    int b = i >> 6, s = i & 63;
    mout[i] = (s >= n_segs[b]) ? 1.0f : 0.0f;
}

// ---------------- host ----------------
extern "C" void kernel_launch(void* const* d_in, const int* in_sizes, int n_in,
                              void* d_out, int out_size, void* d_ws, size_t ws_size,
                              hipStream_t stream) {
    const float* x = (const float*)d_in[0];
    const int* seg_bounds = (const int*)d_in[1];
    const int* n_segs = (const int*)d_in[2];
    const float* cw[7], * cb[7];
    for (int i = 0; i < 7; i++) { cw[i] = (const float*)d_in[3 + 2 * i]; cb[i] = (const float*)d_in[4 + 2 * i]; }
    const float* attn_v = (const float*)d_in[17];
    const float* pos_emb = (const float*)d_in[18];
    const float* in_w = (const float*)d_in[19];
    const float* in_b = (const float*)d_in[20];
    const float* out_w = (const float*)d_in[21];
    const float* out_b = (const float*)d_in[22];
    const float* ff1_w = (const float*)d_in[23];
    const float* ff1_b = (const float*)d_in[24];
    const float* ff2_w = (const float*)d_in[25];
    const float* ff2_b = (const float*)d_in[26];
    const float* ln1_w = (const float*)d_in[27];
    const float* ln1_b = (const float*)d_in[28];
    const float* ln2_w = (const float*)d_in[29];
    const float* ln2_b = (const float*)d_in[30];
    const float* fln_w = (const float*)d_in[31];
    const float* fln_b = (const float*)d_in[32];
    const float* proj_w = (const float*)d_in[33];
    const float* proj_b = (const float*)d_in[34];

    mask_kernel<<<1, 256, 0, stream>>>(n_segs, (float*)d_out + 256 * NCLS);

    size_t off = 0;
    auto alloc = [&](size_t bytes) {
        void* p = (char*)d_ws + off;
        off += (bytes + 255) & ~(size_t)255;
        return p;
    };
    // per-batch row strides (rows of 512 ic)
    const long c0S = 16001L * 512, o1S = 16000L * 512, o2S = 8000L * 512,
               o3S = 4000L * 512, o4S = 2000L * 512, o5S = 1000L * 512, fS = 499L * 768;
    ushort* wbc = (ushort*)alloc(4194304ULL * 2);              // 8.39 MB
    ushort* w0pad = (ushort*)alloc(512ULL * 32 * 2);
    ushort* c0_all = (ushort*)alloc((size_t)BATCH * c0S * 2);  // 65.5 MB
    ushort* o1 = (ushort*)alloc((size_t)BATCH * o1S * 2);      // 65.5 MB
    ushort* o2 = (ushort*)alloc((size_t)BATCH * o2S * 2);      // 32.8 MB
    ushort* o3 = (ushort*)alloc((size_t)BATCH * o3S * 2);      // 16.4 MB
    ushort* o4 = (ushort*)alloc((size_t)BATCH * o4S * 2);      // 8.2 MB
    ushort* o5 = (ushort*)alloc((size_t)BATCH * o5S * 2);      // 4.1 MB
    ushort* feats = (ushort*)alloc((size_t)BATCH * fS * 2);    // 3.07 MB
    float* scores = (float*)alloc((size_t)4 * TP_ * 4);
    float* tokens = (float*)alloc((size_t)256 * DMODEL * 4);
    ushort* tokens_bf = (ushort*)alloc((size_t)256 * DMODEL * 2);
    ushort* oall_bf = (ushort*)alloc((size_t)256 * DMODEL * 2);
    float* ybuf = (float*)alloc((size_t)256 * DMODEL * 4);
    ushort* ybf = (ushort*)alloc((size_t)256 * DMODEL * 2);
    if (off > ws_size) return;  // diagnostic bail

    // transformer-phase slabs alias c0_all (conv phase finished by then):
    // 9.44 + 6.29 + 6.29 + 1.05 = 23.1 MB <= 65.5 MB
    float* qkv_p = (float*)c0_all;                          // 4 x 256x2304
    float* ffh_p = qkv_p + (size_t)4 * 256 * 2304;          // 3 x 256x2048
    float* tmp_p = ffh_p + (size_t)3 * 256 * 2048;          // 8 x 256x768
    ushort* ffh_bf = (ushort*)(tmp_p + (size_t)8 * 256 * 768);

    ushort* wc1 = wbc, * wc2 = wbc + 786432, * wc3 = wbc + 1572864,
          * wc4 = wbc + 2359296, * wc5 = wbc + 2883584, * wc6 = wbc + 3407872;

    convw_kernel<<<dim3(512, 7), 256, 0, stream>>>(cw[1], cw[2], cw[3], cw[4], cw[5], cw[6],
                                                   cw[0], wbc, w0pad);

    // ---- conv stack, batch-merged; grids padded to %8 for XCD swizzle ----
    conv0_mfma<<<dim3(126, 4, BATCH), 256, 0, stream>>>(x, w0pad, cb[0], c0_all, 0, 16001, c0S);
    convT_mfma<3><<<dim3(64, 4, BATCH), 256, 0, stream>>>(
        c0_all, wc1, cb[1], o1, 512, 512, 15999, 0, 0, 16000, c0S, o1S);
    conv0_mfma<<<dim3(125, 4, BATCH), 256, 0, stream>>>(x, w0pad, cb[0], c0_all, 16000, 15999, c0S);
    convT_mfma<3><<<dim3(64, 4, BATCH), 256, 0, stream>>>(
        c0_all, wc1, cb[1], o1, 512, 512, 15999, 8000, 16000, 15998, c0S, o1S);
    convT_mfma<3><<<dim3(64, 4, BATCH), 256, 0, stream>>>(
        o1, wc2, cb[2], o2, 512, 512, 7999, 0, 0, 15998, o1S, o2S);
    convT_mfma<3><<<dim3(32, 4, BATCH), 256, 0, stream>>>(
        o2, wc3, cb[3], o3, 512, 512, 3999, 0, 0, 7998, o2S, o3S);
    convT_mfma<2><<<dim3(16, 4, BATCH), 256, 0, stream>>>(
        o3, wc4, cb[4], o4, 512, 512, 1999, 0, 0, 3998, o3S, o4S);
    convT_mfma<2><<<dim3(8, 4, BATCH), 256, 0, stream>>>(
        o4, wc5, cb[5], o5, 512, 512, 999, 0, 0, 1998, o4S, o5S);
    convT_mfma<2><<<dim3(4, 6, BATCH), 256, 0, stream>>>(
        o5, wc6, cb[6], feats, 512, 768, 499, 0, 0, 998, o5S, fS);

    // ---- pooling ----
    scores_kernel<<<dim3(125, 4), 256, 0, stream>>>(feats, attn_v, scores);
    pool_kernel<<<dim3(SMAX_, 4), 256, 0, stream>>>(feats, scores, seg_bounds, n_segs,
                                                    pos_emb, tokens, tokens_bf);

    // ---- transformer (split-K GEMMs, 256-row tile + 64-wide K-step) ----
    const long qkvSlab = (long)256 * 2304;
    const long tmpSlab = (long)256 * 768;
    const long ffhSlab = (long)256 * 2048;
    for (int l = 0; l < NLAYER; l++) {
        const float* iw = in_w + (size_t)l * 2304 * DMODEL;
        const float* ib = in_b + (size_t)l * 2304;
        const float* ow = out_w + (size_t)l * DMODEL * DMODEL;
        const float* ob = out_b + (size_t)l * DMODEL;
        const float* f1w = ff1_w + (size_t)l * FFDIM * DMODEL;
        const float* f1b = ff1_b + (size_t)l * FFDIM;
        const float* f2w = ff2_w + (size_t)l * DMODEL * FFDIM;
        const float* f2b_ = ff2_b + (size_t)l * DMODEL;

        gemm_sk64<<<dim3(1, 18, 4), 256, 0, stream>>>(tokens_bf, iw, ib, qkv_p, 2304, 768, 192, qkvSlab);
        attn_kernel<<<dim3(12, 4), 256, 0, stream>>>(qkv_p, n_segs, oall_bf, qkvSlab, 4);
        gemm_sk64<<<dim3(1, 6, 4), 256, 0, stream>>>(oall_bf, ow, ob, tmp_p, 768, 768, 192, tmpSlab);
        ln_kernel<<<256, 256, 0, stream>>>(tokens, tmp_p, 4, tmpSlab,
                                           ln1_w + l * DMODEL, ln1_b + l * DMODEL, tokens, tokens_bf);
        gemm_sk64<<<dim3(1, 16, 3), 256, 0, stream>>>(tokens_bf, f1w, f1b, ffh_p, 2048, 768, 256, ffhSlab);
        relu_cast<<<512, 256, 0, stream>>>(ffh_p, ffh_bf, (long)256 * 2048, ffhSlab, 3);
        gemm_sk64<<<dim3(1, 6, 8), 256, 0, stream>>>(ffh_bf, f2w, f2b_, tmp_p, 768, 2048, 256, tmpSlab);
        ln_kernel<<<256, 256, 0, stream>>>(tokens, tmp_p, 8, tmpSlab,
                                           ln2_w + l * DMODEL, ln2_b + l * DMODEL, tokens, tokens_bf);
    }

    // ---- head ----
    ln_kernel<<<256, 256, 0, stream>>>(tokens, nullptr, 0, 0, fln_w, fln_b, ybuf, ybf);
    conv_mfma<1, 1, 0, 0, 1><<<dim3(2, 1, 1), 256, 0, stream>>>(
        ybf, nullptr, proj_w, proj_b, (float*)d_out, 768, NCLS, 256, 0, 0, 0, 0);
}